// Round 8
// baseline (155.519 us; speedup 1.0000x reference)
//
#include <hip/hip_runtime.h>
#include <math.h>

#define NN 256
#define TT 256
#define DD 1024
#define HH 1024

typedef float f32x4 __attribute__((ext_vector_type(4)));
typedef short bf16x8 __attribute__((ext_vector_type(8)));

__device__ inline unsigned short f2bf_rne(float x) {
    unsigned u = __float_as_uint(x);
    unsigned r = (u + 0x7fffu + ((u >> 16) & 1u)) >> 16;
    return (unsigned short)r;
}
__device__ inline float bf2f(unsigned short h) {
    return __uint_as_float(((unsigned)h) << 16);
}

// ---------------------------------------------------------------------------
// Kernel 1: max-pool over token dim. grid (256, 2), block 256.
// R4 build (best measured): all-nontemporal loads, 1 MB contiguous per
// block, 8-deep load pipeline. Thread d4 owns a float4 column.
// ---------------------------------------------------------------------------
__global__ __launch_bounds__(256) void pool_kernel(const float* __restrict__ subs,
                                                   const float* __restrict__ objs,
                                                   float* __restrict__ pooled) {
    const int n = blockIdx.x;
    const int which = blockIdx.y;
    const f32x4* src = reinterpret_cast<const f32x4*>(which == 0 ? subs : objs);
    const int d4 = threadIdx.x;
    const f32x4* base = src + (((size_t)n) << 16) + d4;

    f32x4 a[8];
#pragma unroll
    for (int s = 0; s < 8; ++s) a[s] = (f32x4){-INFINITY, -INFINITY, -INFINITY, -INFINITY};

    for (int k = 0; k < 256; k += 8) {
        f32x4 v[8];
#pragma unroll
        for (int s = 0; s < 8; ++s)
            v[s] = __builtin_nontemporal_load(base + (size_t)(k + s) * 256);
#pragma unroll
        for (int s = 0; s < 8; ++s) {
#pragma unroll
            for (int e = 0; e < 4; ++e) a[s][e] = fmaxf(a[s][e], v[s][e]);
        }
    }
#pragma unroll
    for (int s = 0; s < 4; ++s)
#pragma unroll
        for (int e = 0; e < 4; ++e) a[s][e] = fmaxf(a[s][e], a[s + 4][e]);
    f32x4 m;
#pragma unroll
    for (int e = 0; e < 4; ++e)
        m[e] = fmaxf(fmaxf(a[0][e], a[1][e]), fmaxf(a[2][e], a[3][e]));

    reinterpret_cast<f32x4*>(pooled)[((size_t)(which * NN + n)) * 256 + d4] = m;
}

// ---------------------------------------------------------------------------
// Kernel 2: GEMM via bf16 hi/lo split MFMA (hi*hi + hi*lo + lo*hi ~ fp32).
// out[m][h] = sum_d A[m][d] * W1[h][koff+d] (+b1 if m<256).
// Tiles 64m x 32n, grid (32, 8) = 256 blocks, 4 waves (2m x 2n of 32x16).
// (R4 build — unchanged.)
// ---------------------------------------------------------------------------
__global__ __launch_bounds__(256, 1) void gemm_kernel(const float* __restrict__ A,
                                                      const float* __restrict__ W1,
                                                      const float* __restrict__ b1,
                                                      float* __restrict__ out) {
    __shared__ unsigned short Ah[64 * 40];
    __shared__ unsigned short Al[64 * 40];
    __shared__ unsigned short Bh[32 * 40];
    __shared__ unsigned short Bl[32 * 40];

    const int t = threadIdx.x;
    const int lane = t & 63;
    const int w = t >> 6;
    const int wm = w >> 1, wn = w & 1;
    const int n0 = blockIdx.x * 32;
    const int m0 = blockIdx.y * 64;
    const bool is_sub = (m0 < NN);
    const int koff = is_sub ? 0 : DD;

    const int ar = t >> 2;              // 0..63
    const int akq = (t & 3) * 8;        // 0,8,16,24
    const int br = (t & 127) >> 2;      // 0..31 (threads <128 stage B)
    const int bkq = akq;

    f32x4 acc0 = {0.f, 0.f, 0.f, 0.f};
    f32x4 acc1 = {0.f, 0.f, 0.f, 0.f};

    const int iA0 = (wm * 32 + (lane & 15)) * 40 + (lane >> 4) * 8;
    const int iA1 = (wm * 32 + 16 + (lane & 15)) * 40 + (lane >> 4) * 8;
    const int iB  = (wn * 16 + (lane & 15)) * 40 + (lane >> 4) * 8;

    for (int ch = 0; ch < 32; ++ch) {
        const int kb = ch * 32;
        const float* ap = A + (size_t)(m0 + ar) * DD + kb + akq;
        f32x4 av0 = *(const f32x4*)ap;
        f32x4 av1 = *(const f32x4*)(ap + 4);
        f32x4 bv0, bv1;
        if (t < 128) {
            const float* bp = W1 + (size_t)(n0 + br) * (2 * DD) + koff + kb + bkq;
            bv0 = *(const f32x4*)bp;
            bv1 = *(const f32x4*)(bp + 4);
        }
        __syncthreads();  // previous chunk's compute done

        {
            float xs[8];
#pragma unroll
            for (int e = 0; e < 4; ++e) { xs[e] = av0[e]; xs[4 + e] = av1[e]; }
            unsigned hw[4], lw[4];
#pragma unroll
            for (int p = 0; p < 4; ++p) {
                unsigned short h0 = f2bf_rne(xs[2 * p]);
                unsigned short h1 = f2bf_rne(xs[2 * p + 1]);
                unsigned short l0 = f2bf_rne(xs[2 * p] - bf2f(h0));
                unsigned short l1 = f2bf_rne(xs[2 * p + 1] - bf2f(h1));
                hw[p] = (unsigned)h0 | ((unsigned)h1 << 16);
                lw[p] = (unsigned)l0 | ((unsigned)l1 << 16);
            }
            *(uint4*)&Ah[ar * 40 + akq] = make_uint4(hw[0], hw[1], hw[2], hw[3]);
            *(uint4*)&Al[ar * 40 + akq] = make_uint4(lw[0], lw[1], lw[2], lw[3]);
        }
        if (t < 128) {
            float xs[8];
#pragma unroll
            for (int e = 0; e < 4; ++e) { xs[e] = bv0[e]; xs[4 + e] = bv1[e]; }
            unsigned hw[4], lw[4];
#pragma unroll
            for (int p = 0; p < 4; ++p) {
                unsigned short h0 = f2bf_rne(xs[2 * p]);
                unsigned short h1 = f2bf_rne(xs[2 * p + 1]);
                unsigned short l0 = f2bf_rne(xs[2 * p] - bf2f(h0));
                unsigned short l1 = f2bf_rne(xs[2 * p + 1] - bf2f(h1));
                hw[p] = (unsigned)h0 | ((unsigned)h1 << 16);
                lw[p] = (unsigned)l0 | ((unsigned)l1 << 16);
            }
            *(uint4*)&Bh[br * 40 + bkq] = make_uint4(hw[0], hw[1], hw[2], hw[3]);
            *(uint4*)&Bl[br * 40 + bkq] = make_uint4(lw[0], lw[1], lw[2], lw[3]);
        }
        __syncthreads();  // staging visible

        bf16x8 a0h = *(const bf16x8*)&Ah[iA0];
        bf16x8 a0l = *(const bf16x8*)&Al[iA0];
        bf16x8 a1h = *(const bf16x8*)&Ah[iA1];
        bf16x8 a1l = *(const bf16x8*)&Al[iA1];
        bf16x8 bh  = *(const bf16x8*)&Bh[iB];
        bf16x8 bl  = *(const bf16x8*)&Bl[iB];

        acc0 = __builtin_amdgcn_mfma_f32_16x16x32_bf16(a0h, bh, acc0, 0, 0, 0);
        acc0 = __builtin_amdgcn_mfma_f32_16x16x32_bf16(a0h, bl, acc0, 0, 0, 0);
        acc0 = __builtin_amdgcn_mfma_f32_16x16x32_bf16(a0l, bh, acc0, 0, 0, 0);
        acc1 = __builtin_amdgcn_mfma_f32_16x16x32_bf16(a1h, bh, acc1, 0, 0, 0);
        acc1 = __builtin_amdgcn_mfma_f32_16x16x32_bf16(a1h, bl, acc1, 0, 0, 0);
        acc1 = __builtin_amdgcn_mfma_f32_16x16x32_bf16(a1l, bh, acc1, 0, 0, 0);
    }

    // epilogue: C/D layout col=lane&15, row=(lane>>4)*4+reg; fold b1 for subjects
    const int col = n0 + wn * 16 + (lane & 15);
    const float bias = is_sub ? b1[col] : 0.f;
    const int rb = m0 + wm * 32 + (lane >> 4) * 4;
#pragma unroll
    for (int r = 0; r < 4; ++r) {
        out[(size_t)(rb + r) * HH + col] = acc0[r] + bias;
        out[(size_t)(rb + 16 + r) * HH + col] = acc1[r] + bias;
    }
}

// ---------------------------------------------------------------------------
// Kernel 3: pair scores.  scores[i,j] = sum_h relu(sp[i,h]+op[j,h]) * w2[h] + b2
// grid (16,16), 256 threads, 1 pair/thread. v2: s rows read DIRECTLY from
// global (16 same-ty lanes share each address -> one broadcast L1 access;
// 8 KB/chunk window is L1-resident; sp is L2-hot from the GEMM). LDS keeps
// only the o-tile (per-lane-unique rows). DS instructions per chunk 34->17.
// W2 read block-uniform -> scalar loads.
// ---------------------------------------------------------------------------
#define HC 128

__global__ __launch_bounds__(256) void pair_kernel(const float* __restrict__ sp_op,
                                                   const float* __restrict__ W2,
                                                   const float* __restrict__ b2,
                                                   float* __restrict__ out) {
    __shared__ float oT[16][HC + 4];
    const int t = threadIdx.x;
    const int tx = t & 15, ty = t >> 4;
    const int i0 = blockIdx.y * 16, j0 = blockIdx.x * 16;
    const float* sp = sp_op;                    // rows 0..255 (b1 folded)
    const float* op = sp_op + (size_t)NN * HH;  // rows 256..511
    const float* srow = sp + (size_t)(i0 + ty) * HH;

    const int s_row = t >> 5;       // 0..7; +8 in round 1
    const int s_h = (t & 31) * 4;   // 0..124

    float4 ro[2];
#pragma unroll
    for (int r = 0; r < 2; ++r) {
        const int row = s_row + r * 8;
        ro[r] = *(const float4*)&op[(size_t)(j0 + row) * HH + s_h];
    }

    float acc = 0.f;
    for (int c = 0; c < HH / HC; ++c) {
#pragma unroll
        for (int r = 0; r < 2; ++r) {
            const int row = s_row + r * 8;
            *(float4*)&oT[row][s_h] = ro[r];
        }
        float4 no[2];
        if (c + 1 < HH / HC) {
#pragma unroll
            for (int r = 0; r < 2; ++r) {
                const int row = s_row + r * 8;
                no[r] = *(const float4*)&op[(size_t)(j0 + row) * HH + (c + 1) * HC + s_h];
            }
        }
        __syncthreads();
#pragma unroll
        for (int h4 = 0; h4 < HC / 4; ++h4) {
            float4 s = *(const float4*)&srow[c * HC + h4 * 4];  // L1-broadcast
            float4 o = *(const float4*)&oT[tx][h4 * 4];
            float4 w = *(const float4*)&W2[c * HC + h4 * 4];    // scalar
            acc += fmaxf(s.x + o.x, 0.f) * w.x;
            acc += fmaxf(s.y + o.y, 0.f) * w.y;
            acc += fmaxf(s.z + o.z, 0.f) * w.z;
            acc += fmaxf(s.w + o.w, 0.f) * w.w;
        }
        __syncthreads();
        if (c + 1 < HH / HC) {
#pragma unroll
            for (int r = 0; r < 2; ++r) { ro[r] = no[r]; }
        }
    }
    const int i = i0 + ty, j = j0 + tx;
    const float score = acc + b2[0];
    out[i * NN + j] = (i == j) ? 0.f : score;
}

// ---------------------------------------------------------------------------
extern "C" void kernel_launch(void* const* d_in, const int* in_sizes, int n_in,
                              void* d_out, int out_size, void* d_ws, size_t ws_size,
                              hipStream_t stream) {
    const float* subs = (const float*)d_in[0];
    const float* objs = (const float*)d_in[1];
    const float* W1   = (const float*)d_in[2];
    const float* b1   = (const float*)d_in[3];
    const float* W2   = (const float*)d_in[4];
    const float* b2   = (const float*)d_in[5];
    float* out = (float*)d_out;

    float* pooled = (float*)d_ws;                    // [512][1024] = 2 MB
    float* sp_op  = pooled + (size_t)2 * NN * DD;    // [512][1024] = 2 MB

    pool_kernel<<<dim3(NN, 2), 256, 0, stream>>>(subs, objs, pooled);
    gemm_kernel<<<dim3(HH / 32, (2 * NN) / 64), 256, 0, stream>>>(pooled, W1, b1, sp_op);
    pair_kernel<<<dim3(NN / 16, NN / 16), 256, 0, stream>>>(sp_op, W2, b2, out);
}

// Round 9
// 147.663 us; speedup vs baseline: 1.0532x; 1.0532x over previous
//
#include <hip/hip_runtime.h>
#include <math.h>

#define NN 256
#define TT 256
#define DD 1024
#define HH 1024

typedef float f32x4 __attribute__((ext_vector_type(4)));
typedef short bf16x8 __attribute__((ext_vector_type(8)));

__device__ inline unsigned short f2bf_rne(float x) {
    unsigned u = __float_as_uint(x);
    unsigned r = (u + 0x7fffu + ((u >> 16) & 1u)) >> 16;
    return (unsigned short)r;
}
__device__ inline float bf2f(unsigned short h) {
    return __uint_as_float(((unsigned)h) << 16);
}

// ---------------------------------------------------------------------------
// Kernel 1: max-pool over token dim. grid (256, 2), block 256.
// R4 build (best measured): all-nontemporal loads, 1 MB contiguous per
// block, 8-deep load pipeline. Thread d4 owns a float4 column.
// ---------------------------------------------------------------------------
__global__ __launch_bounds__(256) void pool_kernel(const float* __restrict__ subs,
                                                   const float* __restrict__ objs,
                                                   float* __restrict__ pooled) {
    const int n = blockIdx.x;
    const int which = blockIdx.y;
    const f32x4* src = reinterpret_cast<const f32x4*>(which == 0 ? subs : objs);
    const int d4 = threadIdx.x;
    const f32x4* base = src + (((size_t)n) << 16) + d4;

    f32x4 a[8];
#pragma unroll
    for (int s = 0; s < 8; ++s) a[s] = (f32x4){-INFINITY, -INFINITY, -INFINITY, -INFINITY};

    for (int k = 0; k < 256; k += 8) {
        f32x4 v[8];
#pragma unroll
        for (int s = 0; s < 8; ++s)
            v[s] = __builtin_nontemporal_load(base + (size_t)(k + s) * 256);
#pragma unroll
        for (int s = 0; s < 8; ++s) {
#pragma unroll
            for (int e = 0; e < 4; ++e) a[s][e] = fmaxf(a[s][e], v[s][e]);
        }
    }
#pragma unroll
    for (int s = 0; s < 4; ++s)
#pragma unroll
        for (int e = 0; e < 4; ++e) a[s][e] = fmaxf(a[s][e], a[s + 4][e]);
    f32x4 m;
#pragma unroll
    for (int e = 0; e < 4; ++e)
        m[e] = fmaxf(fmaxf(a[0][e], a[1][e]), fmaxf(a[2][e], a[3][e]));

    reinterpret_cast<f32x4*>(pooled)[((size_t)(which * NN + n)) * 256 + d4] = m;
}

// ---------------------------------------------------------------------------
// Kernel 2: GEMM via bf16 hi/lo split MFMA (hi*hi + hi*lo + lo*hi ~ fp32).
// out[m][h] = sum_d A[m][d] * W1[h][koff+d] (+b1 if m<256).
// Tiles 64m x 32n, grid (32, 8) = 256 blocks, 4 waves (2m x 2n of 32x16).
// (R4 build — unchanged.)
// ---------------------------------------------------------------------------
__global__ __launch_bounds__(256, 1) void gemm_kernel(const float* __restrict__ A,
                                                      const float* __restrict__ W1,
                                                      const float* __restrict__ b1,
                                                      float* __restrict__ out) {
    __shared__ unsigned short Ah[64 * 40];
    __shared__ unsigned short Al[64 * 40];
    __shared__ unsigned short Bh[32 * 40];
    __shared__ unsigned short Bl[32 * 40];

    const int t = threadIdx.x;
    const int lane = t & 63;
    const int w = t >> 6;
    const int wm = w >> 1, wn = w & 1;
    const int n0 = blockIdx.x * 32;
    const int m0 = blockIdx.y * 64;
    const bool is_sub = (m0 < NN);
    const int koff = is_sub ? 0 : DD;

    const int ar = t >> 2;              // 0..63
    const int akq = (t & 3) * 8;        // 0,8,16,24
    const int br = (t & 127) >> 2;      // 0..31 (threads <128 stage B)
    const int bkq = akq;

    f32x4 acc0 = {0.f, 0.f, 0.f, 0.f};
    f32x4 acc1 = {0.f, 0.f, 0.f, 0.f};

    const int iA0 = (wm * 32 + (lane & 15)) * 40 + (lane >> 4) * 8;
    const int iA1 = (wm * 32 + 16 + (lane & 15)) * 40 + (lane >> 4) * 8;
    const int iB  = (wn * 16 + (lane & 15)) * 40 + (lane >> 4) * 8;

    for (int ch = 0; ch < 32; ++ch) {
        const int kb = ch * 32;
        const float* ap = A + (size_t)(m0 + ar) * DD + kb + akq;
        f32x4 av0 = *(const f32x4*)ap;
        f32x4 av1 = *(const f32x4*)(ap + 4);
        f32x4 bv0, bv1;
        if (t < 128) {
            const float* bp = W1 + (size_t)(n0 + br) * (2 * DD) + koff + kb + bkq;
            bv0 = *(const f32x4*)bp;
            bv1 = *(const f32x4*)(bp + 4);
        }
        __syncthreads();  // previous chunk's compute done

        {
            float xs[8];
#pragma unroll
            for (int e = 0; e < 4; ++e) { xs[e] = av0[e]; xs[4 + e] = av1[e]; }
            unsigned hw[4], lw[4];
#pragma unroll
            for (int p = 0; p < 4; ++p) {
                unsigned short h0 = f2bf_rne(xs[2 * p]);
                unsigned short h1 = f2bf_rne(xs[2 * p + 1]);
                unsigned short l0 = f2bf_rne(xs[2 * p] - bf2f(h0));
                unsigned short l1 = f2bf_rne(xs[2 * p + 1] - bf2f(h1));
                hw[p] = (unsigned)h0 | ((unsigned)h1 << 16);
                lw[p] = (unsigned)l0 | ((unsigned)l1 << 16);
            }
            *(uint4*)&Ah[ar * 40 + akq] = make_uint4(hw[0], hw[1], hw[2], hw[3]);
            *(uint4*)&Al[ar * 40 + akq] = make_uint4(lw[0], lw[1], lw[2], lw[3]);
        }
        if (t < 128) {
            float xs[8];
#pragma unroll
            for (int e = 0; e < 4; ++e) { xs[e] = bv0[e]; xs[4 + e] = bv1[e]; }
            unsigned hw[4], lw[4];
#pragma unroll
            for (int p = 0; p < 4; ++p) {
                unsigned short h0 = f2bf_rne(xs[2 * p]);
                unsigned short h1 = f2bf_rne(xs[2 * p + 1]);
                unsigned short l0 = f2bf_rne(xs[2 * p] - bf2f(h0));
                unsigned short l1 = f2bf_rne(xs[2 * p + 1] - bf2f(h1));
                hw[p] = (unsigned)h0 | ((unsigned)h1 << 16);
                lw[p] = (unsigned)l0 | ((unsigned)l1 << 16);
            }
            *(uint4*)&Bh[br * 40 + bkq] = make_uint4(hw[0], hw[1], hw[2], hw[3]);
            *(uint4*)&Bl[br * 40 + bkq] = make_uint4(lw[0], lw[1], lw[2], lw[3]);
        }
        __syncthreads();  // staging visible

        bf16x8 a0h = *(const bf16x8*)&Ah[iA0];
        bf16x8 a0l = *(const bf16x8*)&Al[iA0];
        bf16x8 a1h = *(const bf16x8*)&Ah[iA1];
        bf16x8 a1l = *(const bf16x8*)&Al[iA1];
        bf16x8 bh  = *(const bf16x8*)&Bh[iB];
        bf16x8 bl  = *(const bf16x8*)&Bl[iB];

        acc0 = __builtin_amdgcn_mfma_f32_16x16x32_bf16(a0h, bh, acc0, 0, 0, 0);
        acc0 = __builtin_amdgcn_mfma_f32_16x16x32_bf16(a0h, bl, acc0, 0, 0, 0);
        acc0 = __builtin_amdgcn_mfma_f32_16x16x32_bf16(a0l, bh, acc0, 0, 0, 0);
        acc1 = __builtin_amdgcn_mfma_f32_16x16x32_bf16(a1h, bh, acc1, 0, 0, 0);
        acc1 = __builtin_amdgcn_mfma_f32_16x16x32_bf16(a1h, bl, acc1, 0, 0, 0);
        acc1 = __builtin_amdgcn_mfma_f32_16x16x32_bf16(a1l, bh, acc1, 0, 0, 0);
    }

    // epilogue: C/D layout col=lane&15, row=(lane>>4)*4+reg; fold b1 for subjects
    const int col = n0 + wn * 16 + (lane & 15);
    const float bias = is_sub ? b1[col] : 0.f;
    const int rb = m0 + wm * 32 + (lane >> 4) * 4;
#pragma unroll
    for (int r = 0; r < 4; ++r) {
        out[(size_t)(rb + r) * HH + col] = acc0[r] + bias;
        out[(size_t)(rb + 16 + r) * HH + col] = acc1[r] + bias;
    }
}

// ---------------------------------------------------------------------------
// Kernel 3 v4: pair scores. grid (16,16), 256 threads, 1 pair/thread.
// s-tile (16x1024 = 64 KB) staged in LDS ONCE, XOR-swizzled (col4^(row&7))
// so the 4 concurrent ty-rows per wave ds_read_b128 hit distinct bank quads;
// ONE barrier for the whole kernel. o-row kept in REGISTERS (fixed per
// thread), loaded from global (L2-hot, 4 lanes/addr broadcast), software-
// pipelined in 64-float halves. DS instr per chunk: 64+4 -> 32.
// ---------------------------------------------------------------------------
__global__ __launch_bounds__(256, 1) void pair_kernel(const float* __restrict__ sp_op,
                                                      const float* __restrict__ W2,
                                                      const float* __restrict__ b2,
                                                      float* __restrict__ out) {
    __shared__ f32x4 sT4[16 * 256];   // 64 KB, swizzled
    const int t = threadIdx.x;
    const int tx = t & 15, ty = t >> 4;
    const int i0 = blockIdx.y * 16, j0 = blockIdx.x * 16;
    const float* sp = sp_op;                    // rows 0..255 (b1 folded)
    const float* op = sp_op + (size_t)NN * HH;  // rows 256..511

    // stage full s-tile: thread t stages row t>>4, cols (t&15)+16q (f32x4)
    {
        const int srow = t >> 4;
        const float* sg = sp + (size_t)(i0 + srow) * HH;
#pragma unroll
        for (int q = 0; q < 16; ++q) {
            const int col4 = (t & 15) + 16 * q;
            sT4[srow * 256 + (col4 ^ (srow & 7))] = *(const f32x4*)&sg[col4 * 4];
        }
    }

    const float* orow = op + (size_t)(j0 + tx) * HH;
    const f32x4* w2v = reinterpret_cast<const f32x4*>(W2);

    // prologue: o half 0 (cols 0..63) into registers
    f32x4 og[16], ng[16];
#pragma unroll
    for (int q = 0; q < 16; ++q) og[q] = *(const f32x4*)&orow[q * 4];

    __syncthreads();  // s-tile visible

    float acc = 0.f;
    for (int half = 0; half < 16; ++half) {
        if (half < 15) {
            const int nb = (half + 1) * 64;
#pragma unroll
            for (int q = 0; q < 16; ++q) ng[q] = *(const f32x4*)&orow[nb + q * 4];
        }
#pragma unroll
        for (int h4 = 0; h4 < 16; ++h4) {
            const int col4 = half * 16 + h4;
            f32x4 s = sT4[ty * 256 + (col4 ^ (ty & 7))];
            f32x4 w = w2v[col4];                 // block-uniform -> s_load
            f32x4 o = og[h4];
            acc += fmaxf(s[0] + o[0], 0.f) * w[0];
            acc += fmaxf(s[1] + o[1], 0.f) * w[1];
            acc += fmaxf(s[2] + o[2], 0.f) * w[2];
            acc += fmaxf(s[3] + o[3], 0.f) * w[3];
        }
        if (half < 15) {
#pragma unroll
            for (int q = 0; q < 16; ++q) og[q] = ng[q];
        }
    }
    const int i = i0 + ty, j = j0 + tx;
    const float score = acc + b2[0];
    out[i * NN + j] = (i == j) ? 0.f : score;
}

// ---------------------------------------------------------------------------
extern "C" void kernel_launch(void* const* d_in, const int* in_sizes, int n_in,
                              void* d_out, int out_size, void* d_ws, size_t ws_size,
                              hipStream_t stream) {
    const float* subs = (const float*)d_in[0];
    const float* objs = (const float*)d_in[1];
    const float* W1   = (const float*)d_in[2];
    const float* b1   = (const float*)d_in[3];
    const float* W2   = (const float*)d_in[4];
    const float* b2   = (const float*)d_in[5];
    float* out = (float*)d_out;

    float* pooled = (float*)d_ws;                    // [512][1024] = 2 MB
    float* sp_op  = pooled + (size_t)2 * NN * DD;    // [512][1024] = 2 MB

    pool_kernel<<<dim3(NN, 2), 256, 0, stream>>>(subs, objs, pooled);
    gemm_kernel<<<dim3(HH / 32, (2 * NN) / 64), 256, 0, stream>>>(pooled, W1, b1, sp_op);
    pair_kernel<<<dim3(NN / 16, NN / 16), 256, 0, stream>>>(sp_op, W2, b2, out);
}

// Round 10
// 145.378 us; speedup vs baseline: 1.0698x; 1.0157x over previous
//
#include <hip/hip_runtime.h>
#include <math.h>

#define NN 256
#define TT 256
#define DD 1024
#define HH 1024

typedef float f32x4 __attribute__((ext_vector_type(4)));
typedef short bf16x8 __attribute__((ext_vector_type(8)));

__device__ inline unsigned short f2bf_rne(float x) {
    unsigned u = __float_as_uint(x);
    unsigned r = (u + 0x7fffu + ((u >> 16) & 1u)) >> 16;
    return (unsigned short)r;
}
__device__ inline float bf2f(unsigned short h) {
    return __uint_as_float(((unsigned)h) << 16);
}

// ---------------------------------------------------------------------------
// Kernel 1: max-pool over token dim. grid (256, 2), block 256.
// R4 build (best measured, 145.2 us total): all-nontemporal loads,
// 1 MB contiguous per block, 8-deep load pipeline. Thread d4 owns a
// float4 column. NT = best of 7 pool structures (4.4 TB/s read).
// ---------------------------------------------------------------------------
__global__ __launch_bounds__(256) void pool_kernel(const float* __restrict__ subs,
                                                   const float* __restrict__ objs,
                                                   float* __restrict__ pooled) {
    const int n = blockIdx.x;
    const int which = blockIdx.y;
    const f32x4* src = reinterpret_cast<const f32x4*>(which == 0 ? subs : objs);
    const int d4 = threadIdx.x;
    const f32x4* base = src + (((size_t)n) << 16) + d4;

    f32x4 a[8];
#pragma unroll
    for (int s = 0; s < 8; ++s) a[s] = (f32x4){-INFINITY, -INFINITY, -INFINITY, -INFINITY};

    for (int k = 0; k < 256; k += 8) {
        f32x4 v[8];
#pragma unroll
        for (int s = 0; s < 8; ++s)
            v[s] = __builtin_nontemporal_load(base + (size_t)(k + s) * 256);
#pragma unroll
        for (int s = 0; s < 8; ++s) {
#pragma unroll
            for (int e = 0; e < 4; ++e) a[s][e] = fmaxf(a[s][e], v[s][e]);
        }
    }
#pragma unroll
    for (int s = 0; s < 4; ++s)
#pragma unroll
        for (int e = 0; e < 4; ++e) a[s][e] = fmaxf(a[s][e], a[s + 4][e]);
    f32x4 m;
#pragma unroll
    for (int e = 0; e < 4; ++e)
        m[e] = fmaxf(fmaxf(a[0][e], a[1][e]), fmaxf(a[2][e], a[3][e]));

    reinterpret_cast<f32x4*>(pooled)[((size_t)(which * NN + n)) * 256 + d4] = m;
}

// ---------------------------------------------------------------------------
// Kernel 2: GEMM via bf16 hi/lo split MFMA (hi*hi + hi*lo + lo*hi ~ fp32).
// out[m][h] = sum_d A[m][d] * W1[h][koff+d] (+b1 if m<256).
// Tiles 64m x 32n, grid (32, 8) = 256 blocks, 4 waves (2m x 2n of 32x16).
// (R4 build — unchanged.)
// ---------------------------------------------------------------------------
__global__ __launch_bounds__(256, 1) void gemm_kernel(const float* __restrict__ A,
                                                      const float* __restrict__ W1,
                                                      const float* __restrict__ b1,
                                                      float* __restrict__ out) {
    __shared__ unsigned short Ah[64 * 40];
    __shared__ unsigned short Al[64 * 40];
    __shared__ unsigned short Bh[32 * 40];
    __shared__ unsigned short Bl[32 * 40];

    const int t = threadIdx.x;
    const int lane = t & 63;
    const int w = t >> 6;
    const int wm = w >> 1, wn = w & 1;
    const int n0 = blockIdx.x * 32;
    const int m0 = blockIdx.y * 64;
    const bool is_sub = (m0 < NN);
    const int koff = is_sub ? 0 : DD;

    const int ar = t >> 2;              // 0..63
    const int akq = (t & 3) * 8;        // 0,8,16,24
    const int br = (t & 127) >> 2;      // 0..31 (threads <128 stage B)
    const int bkq = akq;

    f32x4 acc0 = {0.f, 0.f, 0.f, 0.f};
    f32x4 acc1 = {0.f, 0.f, 0.f, 0.f};

    const int iA0 = (wm * 32 + (lane & 15)) * 40 + (lane >> 4) * 8;
    const int iA1 = (wm * 32 + 16 + (lane & 15)) * 40 + (lane >> 4) * 8;
    const int iB  = (wn * 16 + (lane & 15)) * 40 + (lane >> 4) * 8;

    for (int ch = 0; ch < 32; ++ch) {
        const int kb = ch * 32;
        const float* ap = A + (size_t)(m0 + ar) * DD + kb + akq;
        f32x4 av0 = *(const f32x4*)ap;
        f32x4 av1 = *(const f32x4*)(ap + 4);
        f32x4 bv0, bv1;
        if (t < 128) {
            const float* bp = W1 + (size_t)(n0 + br) * (2 * DD) + koff + kb + bkq;
            bv0 = *(const f32x4*)bp;
            bv1 = *(const f32x4*)(bp + 4);
        }
        __syncthreads();  // previous chunk's compute done

        {
            float xs[8];
#pragma unroll
            for (int e = 0; e < 4; ++e) { xs[e] = av0[e]; xs[4 + e] = av1[e]; }
            unsigned hw[4], lw[4];
#pragma unroll
            for (int p = 0; p < 4; ++p) {
                unsigned short h0 = f2bf_rne(xs[2 * p]);
                unsigned short h1 = f2bf_rne(xs[2 * p + 1]);
                unsigned short l0 = f2bf_rne(xs[2 * p] - bf2f(h0));
                unsigned short l1 = f2bf_rne(xs[2 * p + 1] - bf2f(h1));
                hw[p] = (unsigned)h0 | ((unsigned)h1 << 16);
                lw[p] = (unsigned)l0 | ((unsigned)l1 << 16);
            }
            *(uint4*)&Ah[ar * 40 + akq] = make_uint4(hw[0], hw[1], hw[2], hw[3]);
            *(uint4*)&Al[ar * 40 + akq] = make_uint4(lw[0], lw[1], lw[2], lw[3]);
        }
        if (t < 128) {
            float xs[8];
#pragma unroll
            for (int e = 0; e < 4; ++e) { xs[e] = bv0[e]; xs[4 + e] = bv1[e]; }
            unsigned hw[4], lw[4];
#pragma unroll
            for (int p = 0; p < 4; ++p) {
                unsigned short h0 = f2bf_rne(xs[2 * p]);
                unsigned short h1 = f2bf_rne(xs[2 * p + 1]);
                unsigned short l0 = f2bf_rne(xs[2 * p] - bf2f(h0));
                unsigned short l1 = f2bf_rne(xs[2 * p + 1] - bf2f(h1));
                hw[p] = (unsigned)h0 | ((unsigned)h1 << 16);
                lw[p] = (unsigned)l0 | ((unsigned)l1 << 16);
            }
            *(uint4*)&Bh[br * 40 + bkq] = make_uint4(hw[0], hw[1], hw[2], hw[3]);
            *(uint4*)&Bl[br * 40 + bkq] = make_uint4(lw[0], lw[1], lw[2], lw[3]);
        }
        __syncthreads();  // staging visible

        bf16x8 a0h = *(const bf16x8*)&Ah[iA0];
        bf16x8 a0l = *(const bf16x8*)&Al[iA0];
        bf16x8 a1h = *(const bf16x8*)&Ah[iA1];
        bf16x8 a1l = *(const bf16x8*)&Al[iA1];
        bf16x8 bh  = *(const bf16x8*)&Bh[iB];
        bf16x8 bl  = *(const bf16x8*)&Bl[iB];

        acc0 = __builtin_amdgcn_mfma_f32_16x16x32_bf16(a0h, bh, acc0, 0, 0, 0);
        acc0 = __builtin_amdgcn_mfma_f32_16x16x32_bf16(a0h, bl, acc0, 0, 0, 0);
        acc0 = __builtin_amdgcn_mfma_f32_16x16x32_bf16(a0l, bh, acc0, 0, 0, 0);
        acc1 = __builtin_amdgcn_mfma_f32_16x16x32_bf16(a1h, bh, acc1, 0, 0, 0);
        acc1 = __builtin_amdgcn_mfma_f32_16x16x32_bf16(a1h, bl, acc1, 0, 0, 0);
        acc1 = __builtin_amdgcn_mfma_f32_16x16x32_bf16(a1l, bh, acc1, 0, 0, 0);
    }

    // epilogue: C/D layout col=lane&15, row=(lane>>4)*4+reg; fold b1 for subjects
    const int col = n0 + wn * 16 + (lane & 15);
    const float bias = is_sub ? b1[col] : 0.f;
    const int rb = m0 + wm * 32 + (lane >> 4) * 4;
#pragma unroll
    for (int r = 0; r < 4; ++r) {
        out[(size_t)(rb + r) * HH + col] = acc0[r] + bias;
        out[(size_t)(rb + 16 + r) * HH + col] = acc1[r] + bias;
    }
}

// ---------------------------------------------------------------------------
// Kernel 3: pair scores.  scores[i,j] = sum_h relu(sp[i,h]+op[j,h]) * w2[h] + b2
// grid (16,16), 256 threads, 1 pair/thread (R4 build — best measured;
// v2 global-s and v4 big-tile variants both measured worse/neutral).
// LDS dual tiles + register prefetch; W2 block-uniform -> scalar loads.
// ---------------------------------------------------------------------------
#define HC 128

__global__ __launch_bounds__(256) void pair_kernel(const float* __restrict__ sp_op,
                                                   const float* __restrict__ W2,
                                                   const float* __restrict__ b2,
                                                   float* __restrict__ out) {
    __shared__ float sT[16][HC + 4];
    __shared__ float oT[16][HC + 4];
    const int t = threadIdx.x;
    const int tx = t & 15, ty = t >> 4;
    const int i0 = blockIdx.y * 16, j0 = blockIdx.x * 16;
    const float* sp = sp_op;                    // rows 0..255 (b1 folded)
    const float* op = sp_op + (size_t)NN * HH;  // rows 256..511

    const int s_row = t >> 5;       // 0..7; +8 in round 1
    const int s_h = (t & 31) * 4;   // 0..124

    float4 rs[2], ro[2];
#pragma unroll
    for (int r = 0; r < 2; ++r) {
        const int row = s_row + r * 8;
        rs[r] = *(const float4*)&sp[(size_t)(i0 + row) * HH + s_h];
        ro[r] = *(const float4*)&op[(size_t)(j0 + row) * HH + s_h];
    }

    float acc = 0.f;
    for (int c = 0; c < HH / HC; ++c) {
#pragma unroll
        for (int r = 0; r < 2; ++r) {
            const int row = s_row + r * 8;
            *(float4*)&sT[row][s_h] = rs[r];
            *(float4*)&oT[row][s_h] = ro[r];
        }
        float4 ns[2], no[2];
        if (c + 1 < HH / HC) {
#pragma unroll
            for (int r = 0; r < 2; ++r) {
                const int row = s_row + r * 8;
                ns[r] = *(const float4*)&sp[(size_t)(i0 + row) * HH + (c + 1) * HC + s_h];
                no[r] = *(const float4*)&op[(size_t)(j0 + row) * HH + (c + 1) * HC + s_h];
            }
        }
        __syncthreads();
#pragma unroll
        for (int h4 = 0; h4 < HC / 4; ++h4) {
            float4 s = *(const float4*)&sT[ty][h4 * 4];
            float4 o = *(const float4*)&oT[tx][h4 * 4];
            float4 w = *(const float4*)&W2[c * HC + h4 * 4];
            acc += fmaxf(s.x + o.x, 0.f) * w.x;
            acc += fmaxf(s.y + o.y, 0.f) * w.y;
            acc += fmaxf(s.z + o.z, 0.f) * w.z;
            acc += fmaxf(s.w + o.w, 0.f) * w.w;
        }
        __syncthreads();
        if (c + 1 < HH / HC) {
#pragma unroll
            for (int r = 0; r < 2; ++r) { rs[r] = ns[r]; ro[r] = no[r]; }
        }
    }
    const int i = i0 + ty, j = j0 + tx;
    const float score = acc + b2[0];
    out[i * NN + j] = (i == j) ? 0.f : score;
}

// ---------------------------------------------------------------------------
extern "C" void kernel_launch(void* const* d_in, const int* in_sizes, int n_in,
                              void* d_out, int out_size, void* d_ws, size_t ws_size,
                              hipStream_t stream) {
    const float* subs = (const float*)d_in[0];
    const float* objs = (const float*)d_in[1];
    const float* W1   = (const float*)d_in[2];
    const float* b1   = (const float*)d_in[3];
    const float* W2   = (const float*)d_in[4];
    const float* b2   = (const float*)d_in[5];
    float* out = (float*)d_out;

    float* pooled = (float*)d_ws;                    // [512][1024] = 2 MB
    float* sp_op  = pooled + (size_t)2 * NN * DD;    // [512][1024] = 2 MB

    pool_kernel<<<dim3(NN, 2), 256, 0, stream>>>(subs, objs, pooled);
    gemm_kernel<<<dim3(HH / 32, (2 * NN) / 64), 256, 0, stream>>>(pooled, W1, b1, sp_op);
    pair_kernel<<<dim3(NN / 16, NN / 16), 256, 0, stream>>>(sp_op, W2, b2, out);
}